// Round 5
// baseline (748.918 us; speedup 1.0000x reference)
//
#include <hip/hip_runtime.h>
#include <hip/hip_bf16.h>

// N=100000, E=600000, H=128, Z=64, IN=6. Mid layers: fused N=256 MFMA bf16 GEMM
// over K=192 ([f(128)|z(64)]); the 6 input-feature cols are applied in the
// gather epilogue as two 6x128 matvecs (in[n]@Ws_in, nb_in[n]@Wn_in).
// f, h, partial all bf16; epilogue + final projection fused into CSR gather.

typedef short short8v __attribute__((ext_vector_type(8)));
typedef float float4v __attribute__((ext_vector_type(4)));

static __device__ __forceinline__ unsigned short f2b(float x) {
  union { float f; unsigned u; } v; v.f = x;
  unsigned r = v.u + 0x7FFF + ((v.u >> 16) & 1);
  return (unsigned short)(r >> 16);
}
static __device__ __forceinline__ float b2f(unsigned short x) {
  union { unsigned u; float f; } v; v.u = ((unsigned)x) << 16;
  return v.f;
}

// ---------------- CSR build ----------------
__global__ __launch_bounds__(256) void k_hist(
    const int* __restrict__ edges, int* __restrict__ count, int nE) {
  int e = blockIdx.x * blockDim.x + threadIdx.x;
  if (e >= nE) return;
  atomicAdd(&count[edges[2 * e + 1]], 1);
}

__global__ __launch_bounds__(256) void k_scan_part(
    const int* __restrict__ count, int* __restrict__ partial, int nN) {
  __shared__ int s[256];
  int t = threadIdx.x;
  int n = blockIdx.x * 256 + t;
  s[t] = (n < nN) ? count[n] : 0;
  __syncthreads();
  for (int off = 128; off > 0; off >>= 1) {
    if (t < off) s[t] += s[t + off];
    __syncthreads();
  }
  if (t == 0) partial[blockIdx.x] = s[0];
}

__global__ __launch_bounds__(512) void k_scan_mid(
    int* __restrict__ partial, int* __restrict__ row_ptr, int nb, int nN, int nE) {
  __shared__ int s[512];
  int t = threadIdx.x;
  int v = (t < nb) ? partial[t] : 0;
  s[t] = v;
  __syncthreads();
  for (int off = 1; off < 512; off <<= 1) {
    int add = (t >= off) ? s[t - off] : 0;
    __syncthreads();
    s[t] += add;
    __syncthreads();
  }
  if (t < nb) partial[t] = s[t] - v;  // exclusive
  if (t == 0) row_ptr[nN] = nE;
}

__global__ __launch_bounds__(256) void k_scan_out(
    const int* __restrict__ count, const int* __restrict__ partial,
    int* __restrict__ row_ptr, int* __restrict__ cursor,
    float* __restrict__ invdeg, int nN) {
  __shared__ int s[256];
  int t = threadIdx.x;
  int n = blockIdx.x * 256 + t;
  int v = (n < nN) ? count[n] : 0;
  s[t] = v;
  __syncthreads();
  for (int off = 1; off < 256; off <<= 1) {
    int add = (t >= off) ? s[t - off] : 0;
    __syncthreads();
    s[t] += add;
    __syncthreads();
  }
  if (n < nN) {
    int excl = s[t] - v + partial[blockIdx.x];
    row_ptr[n] = excl;
    cursor[n] = excl;
    invdeg[n] = 1.0f / fmaxf((float)v, 1.0f);
  }
}

__global__ __launch_bounds__(256) void k_fill(
    const int* __restrict__ edges, int* __restrict__ cursor,
    int* __restrict__ csr_src, int nE) {
  int e = blockIdx.x * blockDim.x + threadIdx.x;
  if (e >= nE) return;
  int src = edges[2 * e], dst = edges[2 * e + 1];
  int pos = atomicAdd(&cursor[dst], 1);
  csr_src[pos] = src;
}

// ---------------- weight prep: Wt[i][col 256][k 192] bf16 (f,z rows only) ----
__global__ __launch_bounds__(256) void k_prepw(
    const float* __restrict__ Wbn, const float* __restrict__ Wbs,
    unsigned short* __restrict__ Wt) {
  int t = blockIdx.x * 256 + threadIdx.x;
  if (t >= 4 * 256 * 192) return;
  int k = t % 192;
  int c = (t / 192) % 256;
  int i = t / (192 * 256);
  float v = (c < 128) ? Wbn[((size_t)i * 198 + k) * 128 + c]
                      : Wbs[((size_t)i * 198 + k) * 128 + (c - 128)];
  Wt[t] = f2b(v);
}

// ---------------- input-feature aggregation (6 feats) ----------------
__global__ __launch_bounds__(256) void k_nbin(
    const int* __restrict__ row_ptr, const int* __restrict__ csr_src,
    const float* __restrict__ vert, const float* __restrict__ vp,
    const float* __restrict__ invdeg, float* __restrict__ nb_in, int nN) {
  int n = blockIdx.x * blockDim.x + threadIdx.x;
  if (n >= nN) return;
  float a[6] = {0, 0, 0, 0, 0, 0};
  int beg = row_ptr[n], end = row_ptr[n + 1];
  for (int j = beg; j < end; ++j) {
    int s = csr_src[j];
#pragma unroll
    for (int k = 0; k < 3; ++k) {
      a[k] += vert[s * 3 + k];
      a[3 + k] += vp[s * 3 + k];
    }
  }
  float inv = invdeg[n];
#pragma unroll
  for (int k = 0; k < 6; ++k) nb_in[n * 6 + k] = a[k] * inv;
}

// ---------------- layer 0 (K=12, writes bf16 f) ----------------
__global__ __launch_bounds__(256) void k_layer0(
    const float* __restrict__ vert, const float* __restrict__ vp,
    const float* __restrict__ nb_in, const float* __restrict__ W0s,
    const float* __restrict__ W0n, const float* __restrict__ b0,
    unsigned short* __restrict__ fb, int nN) {
  int t = blockIdx.x * blockDim.x + threadIdx.x;
  int n = t >> 7, hh = t & 127;
  if (n >= nN) return;
  float acc = b0[hh];
#pragma unroll
  for (int k = 0; k < 3; ++k) {
    acc += vert[n * 3 + k] * W0s[k * 128 + hh];
    acc += vp[n * 3 + k] * W0s[(3 + k) * 128 + hh];
    acc += nb_in[n * 6 + k] * W0n[k * 128 + hh];
    acc += nb_in[n * 6 + 3 + k] * W0n[(3 + k) * 128 + hh];
  }
  fb[(size_t)n * 128 + hh] = f2b(fmaxf(acc, 0.0f));
}

// ---------------- fused MFMA GEMM: [h | partial] = [f,z] @ [Wn | Ws] ----------
// x row (K=192): [f(128) | z(64)]. Block: 64 rows x 256 cols, 4 waves.
__global__ __launch_bounds__(256) void k_mfma(
    const unsigned short* __restrict__ fb, const float* __restrict__ z,
    const unsigned short* __restrict__ Wt, unsigned short* __restrict__ pb,
    unsigned short* __restrict__ hb, int nN) {
  __shared__ unsigned short xs[64 * 200];  // pitch 200 shorts: 2-way bank alias (free)
  int t = threadIdx.x;
  int n0 = blockIdx.x * 64;

  // stage f (cols 0..127), 16B per thread-iter
  for (int i = t; i < 64 * 16; i += 256) {
    int r = i >> 4, ck = (i & 15) * 8;
    int gn = min(n0 + r, nN - 1);
    *(short8v*)&xs[r * 200 + ck] = *(const short8v*)&fb[(size_t)gn * 128 + ck];
  }
  // stage z (cols 128..191), f32->bf16
  for (int i = t; i < 64 * 16; i += 256) {
    int r = i >> 4, ck = (i & 15) * 4;
    int gn = min(n0 + r, nN - 1);
    float4 v = *(const float4*)&z[(size_t)gn * 64 + ck];
    ushort4 o = {f2b(v.x), f2b(v.y), f2b(v.z), f2b(v.w)};
    *(ushort4*)&xs[r * 200 + 128 + ck] = o;
  }
  __syncthreads();

  int w = t >> 6, l = t & 63;
  int c0 = w * 64;
  int lr = l & 15;
  int lk = (l >> 4) * 8;

  float4v acc[4][4];
#pragma unroll
  for (int mt = 0; mt < 4; ++mt)
#pragma unroll
    for (int nt = 0; nt < 4; ++nt)
      acc[mt][nt] = (float4v){0.f, 0.f, 0.f, 0.f};

#pragma unroll
  for (int ks = 0; ks < 6; ++ks) {
    short8v a[4], b[4];
#pragma unroll
    for (int nt = 0; nt < 4; ++nt)
      b[nt] = *(const short8v*)&Wt[(size_t)(c0 + nt * 16 + lr) * 192 + ks * 32 + lk];
#pragma unroll
    for (int mt = 0; mt < 4; ++mt)
      a[mt] = *(const short8v*)&xs[(mt * 16 + lr) * 200 + ks * 32 + lk];
#pragma unroll
    for (int mt = 0; mt < 4; ++mt)
#pragma unroll
      for (int nt = 0; nt < 4; ++nt)
        acc[mt][nt] = __builtin_amdgcn_mfma_f32_16x16x32_bf16(
            a[mt], b[nt], acc[mt][nt], 0, 0, 0);
  }

  // store: C layout col=lane&15, row=(lane>>4)*4+j
  int rbase = (l >> 4) * 4;
#pragma unroll
  for (int mt = 0; mt < 4; ++mt) {
#pragma unroll
    for (int nt = 0; nt < 4; ++nt) {
      int col = c0 + nt * 16 + lr;
#pragma unroll
      for (int j = 0; j < 4; ++j) {
        int row = n0 + mt * 16 + rbase + j;
        if (row < nN) {
          float v = acc[mt][nt][j];
          if (col < 128) hb[(size_t)row * 128 + col] = f2b(v);
          else           pb[(size_t)row * 128 + (col - 128)] = f2b(v);
        }
      }
    }
  }
}

// ---- gather h + epilogue: f = relu(pb + in@Ws_in + invdeg*sum(h[src]) + nb_in@Wn_in + b)
// FINAL=1 additionally computes h3[n] = f[n] @ Wln (3 floats) via 32-lane reduce.
template <int FINAL>
__global__ __launch_bounds__(256) void k_gather_ep(
    const unsigned short* __restrict__ hb, const int* __restrict__ row_ptr,
    const int* __restrict__ csr_src, const float* __restrict__ invdeg,
    const unsigned short* __restrict__ pb, const float* __restrict__ nb_in,
    const float* __restrict__ vert, const float* __restrict__ vp,
    const float* __restrict__ Wn_in, const float* __restrict__ Ws_in,
    const float* __restrict__ bias, unsigned short* __restrict__ fb,
    const float* __restrict__ Wln, float4* __restrict__ h3, int nN) {
  int t = blockIdx.x * 256 + threadIdx.x;
  int n = t >> 5, c = t & 31;  // cols 4c..4c+3
  if (n >= nN) return;
  int beg = row_ptr[n], end = row_ptr[n + 1];
  float a0 = 0, a1 = 0, a2 = 0, a3 = 0;
  int j = beg;
  for (; j + 1 < end; j += 2) {
    int s0 = csr_src[j], s1 = csr_src[j + 1];
    ushort4 v0 = *(const ushort4*)&hb[(size_t)s0 * 128 + c * 4];
    ushort4 v1 = *(const ushort4*)&hb[(size_t)s1 * 128 + c * 4];
    a0 += b2f(v0.x) + b2f(v1.x);
    a1 += b2f(v0.y) + b2f(v1.y);
    a2 += b2f(v0.z) + b2f(v1.z);
    a3 += b2f(v0.w) + b2f(v1.w);
  }
  if (j < end) {
    int s0 = csr_src[j];
    ushort4 v0 = *(const ushort4*)&hb[(size_t)s0 * 128 + c * 4];
    a0 += b2f(v0.x); a1 += b2f(v0.y); a2 += b2f(v0.z); a3 += b2f(v0.w);
  }
  // input-feature corrections (6x128 matvecs, L2-resident weights)
  float in6[6], nb6[6];
#pragma unroll
  for (int k = 0; k < 3; ++k) {
    in6[k] = vert[n * 3 + k];
    in6[3 + k] = vp[n * 3 + k];
  }
#pragma unroll
  for (int k = 0; k < 6; ++k) nb6[k] = nb_in[n * 6 + k];
  float cx = 0, cy = 0, cz = 0, cw = 0;
#pragma unroll
  for (int k = 0; k < 6; ++k) {
    float4 wn = *(const float4*)&Wn_in[k * 128 + c * 4];
    float4 wsv = *(const float4*)&Ws_in[k * 128 + c * 4];
    cx += nb6[k] * wn.x + in6[k] * wsv.x;
    cy += nb6[k] * wn.y + in6[k] * wsv.y;
    cz += nb6[k] * wn.z + in6[k] * wsv.z;
    cw += nb6[k] * wn.w + in6[k] * wsv.w;
  }
  float inv = invdeg[n];
  ushort4 pv4 = *(const ushort4*)&pb[(size_t)n * 128 + c * 4];
  float4 bv = *(const float4*)&bias[c * 4];
  ushort4 o;
  o.x = f2b(fmaxf(b2f(pv4.x) + a0 * inv + bv.x + cx, 0.f));
  o.y = f2b(fmaxf(b2f(pv4.y) + a1 * inv + bv.y + cy, 0.f));
  o.z = f2b(fmaxf(b2f(pv4.z) + a2 * inv + bv.z + cz, 0.f));
  o.w = f2b(fmaxf(b2f(pv4.w) + a3 * inv + bv.w + cw, 0.f));
  *(ushort4*)&fb[(size_t)n * 128 + c * 4] = o;

  if (FINAL) {
    float f0 = b2f(o.x), f1 = b2f(o.y), f2 = b2f(o.z), f3 = b2f(o.w);
    float p[3];
#pragma unroll
    for (int oo = 0; oo < 3; ++oo) {
      int cc = c * 4;
      p[oo] = f0 * Wln[cc * 3 + oo] + f1 * Wln[(cc + 1) * 3 + oo] +
              f2 * Wln[(cc + 2) * 3 + oo] + f3 * Wln[(cc + 3) * 3 + oo];
    }
#pragma unroll
    for (int off = 16; off >= 1; off >>= 1) {  // reduce within 32-lane node group
      p[0] += __shfl_xor(p[0], off);
      p[1] += __shfl_xor(p[1], off);
      p[2] += __shfl_xor(p[2], off);
    }
    if (c == 0) {
      float4 ov = {p[0], p[1], p[2], 0.0f};
      h3[n] = ov;
    }
  }
}

// ---------------- final aggregation + output ----------------
__global__ __launch_bounds__(256) void k_gather3(
    const float4* __restrict__ h3, const int* __restrict__ row_ptr,
    const int* __restrict__ csr_src, const float* __restrict__ invdeg,
    float4* __restrict__ nb3, int nN) {
  int n = blockIdx.x * 256 + threadIdx.x;
  if (n >= nN) return;
  int beg = row_ptr[n], end = row_ptr[n + 1];
  float4 acc = {0, 0, 0, 0};
  for (int j = beg; j < end; ++j) {
    float4 v = h3[csr_src[j]];
    acc.x += v.x; acc.y += v.y; acc.z += v.z;
  }
  float inv = invdeg[n];
  float4 o = {acc.x * inv, acc.y * inv, acc.z * inv, 0.0f};
  nb3[n] = o;
}

__global__ __launch_bounds__(256) void k_final_out(
    const unsigned short* __restrict__ fb, const float* __restrict__ Wls,
    const float4* __restrict__ nb3, const float* __restrict__ bl,
    float* __restrict__ out, int nN) {
  int n = blockIdx.x * 4 + (threadIdx.x >> 6);
  int l = threadIdx.x & 63;
  if (n >= nN) return;
  float a0 = b2f(fb[(size_t)n * 128 + l]), a1 = b2f(fb[(size_t)n * 128 + 64 + l]);
  float p[3];
#pragma unroll
  for (int o = 0; o < 3; ++o)
    p[o] = a0 * Wls[l * 3 + o] + a1 * Wls[(64 + l) * 3 + o];
#pragma unroll
  for (int off = 32; off >= 1; off >>= 1) {
    p[0] += __shfl_xor(p[0], off);
    p[1] += __shfl_xor(p[1], off);
    p[2] += __shfl_xor(p[2], off);
  }
  if (l == 0) {
    float4 nv = nb3[n];
    out[n * 3 + 0] = p[0] + nv.x + bl[0];
    out[n * 3 + 1] = p[1] + nv.y + bl[1];
    out[n * 3 + 2] = p[2] + nv.z + bl[2];
  }
}

extern "C" void kernel_launch(void* const* d_in, const int* in_sizes, int n_in,
                              void* d_out, int out_size, void* d_ws, size_t ws_size,
                              hipStream_t stream) {
  const float* vert = (const float*)d_in[0];
  const int* edges = (const int*)d_in[1];
  const float* vp = (const float*)d_in[2];
  const float* z = (const float*)d_in[3];
  const float* W0s = (const float*)d_in[4];
  const float* W0n = (const float*)d_in[5];
  const float* b0 = (const float*)d_in[6];
  const float* Wbs = (const float*)d_in[7];
  const float* Wbn = (const float*)d_in[8];
  const float* bb = (const float*)d_in[9];
  const float* Wls = (const float*)d_in[10];
  const float* Wln = (const float*)d_in[11];
  const float* bl = (const float*)d_in[12];
  int nN = in_sizes[0] / 3;
  int nE = in_sizes[1] / 2;

  float* ws = (float*)d_ws;
  size_t o = 0;
  float* invdeg = ws + o; o += (size_t)nN;
  float* nb_in = ws + o; o += (size_t)nN * 6;
  o = (o + 3) & ~(size_t)3;
  unsigned short* pb = (unsigned short*)(ws + o); o += (size_t)nN * 64;
  unsigned short* hb = (unsigned short*)(ws + o); o += (size_t)nN * 64;
  unsigned short* fb = (unsigned short*)(ws + o); o += (size_t)nN * 64;
  unsigned short* Wt = (unsigned short*)(ws + o); o += (size_t)4 * 256 * 192 / 2;
  float* h3 = ws + o; o += (size_t)nN * 4;
  float* nb3 = ws + o; o += (size_t)nN * 4;
  int* ibase = (int*)(ws + o);
  int* count = ibase;              // nN
  int* row_ptr = ibase + nN;       // nN+1 (+pad)
  int* cursor = row_ptr + nN + 4;  // nN
  int* pscan = cursor + nN;        // 512
  int* csr_src = pscan + 512;      // nE

  int nbScan = (nN + 255) / 256;

  hipMemsetAsync(count, 0, (size_t)nN * sizeof(int), stream);
  k_hist<<<(nE + 255) / 256, 256, 0, stream>>>(edges, count, nE);
  k_scan_part<<<nbScan, 256, 0, stream>>>(count, pscan, nN);
  k_scan_mid<<<1, 512, 0, stream>>>(pscan, row_ptr, nbScan, nN, nE);
  k_scan_out<<<nbScan, 256, 0, stream>>>(count, pscan, row_ptr, cursor, invdeg, nN);
  k_fill<<<(nE + 255) / 256, 256, 0, stream>>>(edges, cursor, csr_src, nE);
  k_prepw<<<(4 * 256 * 192 + 255) / 256, 256, 0, stream>>>(Wbn, Wbs, Wt);

  k_nbin<<<nbScan, 256, 0, stream>>>(row_ptr, csr_src, vert, vp, invdeg, nb_in, nN);
  k_layer0<<<(int)(((size_t)nN * 128 + 255) / 256), 256, 0, stream>>>(
      vert, vp, nb_in, W0s, W0n, b0, fb, nN);

  for (int i = 0; i < 4; ++i) {
    const float* zi = z + (size_t)i * nN * 64;
    const float* Wn_in = Wbn + ((size_t)i * 198 + 192) * 128;
    const float* Ws_in = Wbs + ((size_t)i * 198 + 192) * 128;
    k_mfma<<<(nN + 63) / 64, 256, 0, stream>>>(
        fb, zi, Wt + (size_t)i * 256 * 192, pb, hb, nN);
    if (i < 3)
      k_gather_ep<0><<<(int)(((size_t)nN * 32 + 255) / 256), 256, 0, stream>>>(
          hb, row_ptr, csr_src, invdeg, pb, nb_in, vert, vp, Wn_in, Ws_in,
          bb + (size_t)i * 128, fb, nullptr, nullptr, nN);
    else
      k_gather_ep<1><<<(int)(((size_t)nN * 32 + 255) / 256), 256, 0, stream>>>(
          hb, row_ptr, csr_src, invdeg, pb, nb_in, vert, vp, Wn_in, Ws_in,
          bb + (size_t)i * 128, fb, Wln, (float4*)h3, nN);
  }

  k_gather3<<<nbScan, 256, 0, stream>>>(
      (const float4*)h3, row_ptr, csr_src, invdeg, (float4*)nb3, nN);
  k_final_out<<<(nN + 3) / 4, 256, 0, stream>>>(
      fb, Wls, (const float4*)nb3, bl, (float*)d_out, nN);
}

// Round 6
// 703.701 us; speedup vs baseline: 1.0643x; 1.0643x over previous
//
#include <hip/hip_runtime.h>
#include <hip/hip_bf16.h>

// N=100000, E=600000, H=128, Z=64, IN=6, K=224 ([f(128)|z(64)|in(6)|pad]).
// Mid layers fully fused: one kernel per layer does {gather-activation staging
// of f_prev into LDS} + {MFMA GEMM -> h|p (bf16)}. h/p double-buffered A/B.
// Final layer: gather_fin computes f4 in regs, emits f4@Wln and f4@Wls+bl;
// k_out aggregates the 16B/node projection buffer.

typedef short short8v __attribute__((ext_vector_type(8)));
typedef float float4v __attribute__((ext_vector_type(4)));

static __device__ __forceinline__ unsigned short f2b(float x) {
  union { float f; unsigned u; } v; v.f = x;
  unsigned r = v.u + 0x7FFF + ((v.u >> 16) & 1);
  return (unsigned short)(r >> 16);
}
static __device__ __forceinline__ float b2f(unsigned short x) {
  union { unsigned u; float f; } v; v.u = ((unsigned)x) << 16;
  return v.f;
}

// ---------------- CSR build ----------------
__global__ __launch_bounds__(256) void k_hist(
    const int* __restrict__ edges, int* __restrict__ count, int nE) {
  int e = blockIdx.x * blockDim.x + threadIdx.x;
  if (e >= nE) return;
  atomicAdd(&count[edges[2 * e + 1]], 1);
}

__global__ __launch_bounds__(256) void k_scan_part(
    const int* __restrict__ count, int* __restrict__ partial, int nN) {
  __shared__ int s[256];
  int t = threadIdx.x;
  int n = blockIdx.x * 256 + t;
  s[t] = (n < nN) ? count[n] : 0;
  __syncthreads();
  for (int off = 128; off > 0; off >>= 1) {
    if (t < off) s[t] += s[t + off];
    __syncthreads();
  }
  if (t == 0) partial[blockIdx.x] = s[0];
}

__global__ __launch_bounds__(512) void k_scan_mid(
    int* __restrict__ partial, int* __restrict__ row_ptr, int nb, int nN, int nE) {
  __shared__ int s[512];
  int t = threadIdx.x;
  int v = (t < nb) ? partial[t] : 0;
  s[t] = v;
  __syncthreads();
  for (int off = 1; off < 512; off <<= 1) {
    int add = (t >= off) ? s[t - off] : 0;
    __syncthreads();
    s[t] += add;
    __syncthreads();
  }
  if (t < nb) partial[t] = s[t] - v;  // exclusive
  if (t == 0) row_ptr[nN] = nE;
}

__global__ __launch_bounds__(256) void k_scan_out(
    const int* __restrict__ count, const int* __restrict__ partial,
    int* __restrict__ row_ptr, int* __restrict__ cursor,
    float* __restrict__ invdeg, int nN) {
  __shared__ int s[256];
  int t = threadIdx.x;
  int n = blockIdx.x * 256 + t;
  int v = (n < nN) ? count[n] : 0;
  s[t] = v;
  __syncthreads();
  for (int off = 1; off < 256; off <<= 1) {
    int add = (t >= off) ? s[t - off] : 0;
    __syncthreads();
    s[t] += add;
    __syncthreads();
  }
  if (n < nN) {
    int excl = s[t] - v + partial[blockIdx.x];
    row_ptr[n] = excl;
    cursor[n] = excl;
    invdeg[n] = 1.0f / fmaxf((float)v, 1.0f);
  }
}

__global__ __launch_bounds__(256) void k_fill(
    const int* __restrict__ edges, int* __restrict__ cursor,
    int* __restrict__ csr_src, int nE) {
  int e = blockIdx.x * blockDim.x + threadIdx.x;
  if (e >= nE) return;
  int src = edges[2 * e], dst = edges[2 * e + 1];
  int pos = atomicAdd(&cursor[dst], 1);
  csr_src[pos] = src;
}

// ---------------- weight prep: Wt[i][col 256][k 224] bf16 ----------------
__global__ __launch_bounds__(256) void k_prepw(
    const float* __restrict__ Wbn, const float* __restrict__ Wbs,
    unsigned short* __restrict__ Wt) {
  int t = blockIdx.x * 256 + threadIdx.x;
  if (t >= 4 * 256 * 224) return;
  int k = t % 224;
  int c = (t / 224) % 256;
  int i = t / (224 * 256);
  float v = 0.f;
  if (k < 198)
    v = (c < 128) ? Wbn[((size_t)i * 198 + k) * 128 + c]
                  : Wbs[((size_t)i * 198 + k) * 128 + (c - 128)];
  Wt[t] = f2b(v);
}

// ---------------- input-feature aggregation (6 feats) ----------------
__global__ __launch_bounds__(256) void k_nbin(
    const int* __restrict__ row_ptr, const int* __restrict__ csr_src,
    const float* __restrict__ vert, const float* __restrict__ vp,
    const float* __restrict__ invdeg, float* __restrict__ nb_in, int nN) {
  int n = blockIdx.x * blockDim.x + threadIdx.x;
  if (n >= nN) return;
  float a[6] = {0, 0, 0, 0, 0, 0};
  int beg = row_ptr[n], end = row_ptr[n + 1];
  for (int j = beg; j < end; ++j) {
    int s = csr_src[j];
#pragma unroll
    for (int k = 0; k < 3; ++k) {
      a[k] += vert[s * 3 + k];
      a[3 + k] += vp[s * 3 + k];
    }
  }
  float inv = invdeg[n];
#pragma unroll
  for (int k = 0; k < 6; ++k) nb_in[n * 6 + k] = a[k] * inv;
}

// ---------------- layer 0 (K=12, writes bf16 f0) ----------------
__global__ __launch_bounds__(256) void k_layer0(
    const float* __restrict__ vert, const float* __restrict__ vp,
    const float* __restrict__ nb_in, const float* __restrict__ W0s,
    const float* __restrict__ W0n, const float* __restrict__ b0,
    unsigned short* __restrict__ fb, int nN) {
  int t = blockIdx.x * blockDim.x + threadIdx.x;
  int n = t >> 7, hh = t & 127;
  if (n >= nN) return;
  float acc = b0[hh];
#pragma unroll
  for (int k = 0; k < 3; ++k) {
    acc += vert[n * 3 + k] * W0s[k * 128 + hh];
    acc += vp[n * 3 + k] * W0s[(3 + k) * 128 + hh];
    acc += nb_in[n * 6 + k] * W0n[k * 128 + hh];
    acc += nb_in[n * 6 + 3 + k] * W0n[(3 + k) * 128 + hh];
  }
  fb[(size_t)n * 128 + hh] = f2b(fmaxf(acc, 0.0f));
}

// ---------------- fused layer kernel ----------------
// GATHER=0: f rows come from fb. GATHER=1: f rows = relu(pb_in + invdeg*sum
// hb_in[src] + bias_prev), computed during staging.
// Then MFMA: [h|p] = [f,z,in] @ [Wn|Ws], K=224. 64 rows x 256 cols, 4 waves.
template <int GATHER>
__global__ __launch_bounds__(256) void k_fused(
    const unsigned short* __restrict__ fb,
    const unsigned short* __restrict__ hb_in,
    const unsigned short* __restrict__ pb_in,
    const int* __restrict__ row_ptr, const int* __restrict__ csr_src,
    const float* __restrict__ invdeg, const float* __restrict__ bias_prev,
    const float* __restrict__ z, const float* __restrict__ vert,
    const float* __restrict__ vp, const unsigned short* __restrict__ Wt,
    unsigned short* __restrict__ pb_out, unsigned short* __restrict__ hb_out,
    int nN) {
  __shared__ unsigned short xs[64 * 232];
  int t = threadIdx.x;
  int n0 = blockIdx.x * 64;

  // stage z (cols 128..191), f32->bf16
  for (int i = t; i < 64 * 16; i += 256) {
    int r = i >> 4, ck = (i & 15) * 4;
    int gn = min(n0 + r, nN - 1);
    float4 v = *(const float4*)&z[(size_t)gn * 64 + ck];
    ushort4 o = {f2b(v.x), f2b(v.y), f2b(v.z), f2b(v.w)};
    *(ushort4*)&xs[r * 232 + 128 + ck] = o;
  }
  // stage in (cols 192..197) + zero pad (198..223)
  for (int i = t; i < 64 * 16; i += 256) {
    int r = i >> 4, p = i & 15;
    int c = 192 + 2 * p;
    int gn = min(n0 + r, nN - 1);
    float v0 = 0.f, v1 = 0.f;
    if (c < 198)     v0 = (c < 195) ? vert[gn * 3 + c - 192] : vp[gn * 3 + c - 195];
    if (c + 1 < 198) v1 = (c + 1 < 195) ? vert[gn * 3 + c - 191] : vp[gn * 3 + c - 194];
    ushort2 o = {f2b(v0), f2b(v1)};
    *(ushort2*)&xs[r * 232 + c] = o;
  }
  // stage f (cols 0..127)
  if (GATHER == 0) {
    for (int i = t; i < 64 * 16; i += 256) {
      int r = i >> 4, ck = (i & 15) * 8;
      int gn = min(n0 + r, nN - 1);
      *(short8v*)&xs[r * 232 + ck] = *(const short8v*)&fb[(size_t)gn * 128 + ck];
    }
  } else {
    int g = t >> 5;   // 8 groups of 32 lanes
    int c = t & 31;   // cols 4c..4c+3
    for (int i = 0; i < 8; ++i) {
      int r = g * 8 + i;
      int gn = min(n0 + r, nN - 1);
      int beg = row_ptr[gn], end = row_ptr[gn + 1];
      float a0 = 0, a1 = 0, a2 = 0, a3 = 0;
      int j = beg;
      for (; j + 3 < end; j += 4) {
        int s0 = csr_src[j], s1 = csr_src[j + 1];
        int s2 = csr_src[j + 2], s3 = csr_src[j + 3];
        ushort4 v0 = *(const ushort4*)&hb_in[(size_t)s0 * 128 + c * 4];
        ushort4 v1 = *(const ushort4*)&hb_in[(size_t)s1 * 128 + c * 4];
        ushort4 v2 = *(const ushort4*)&hb_in[(size_t)s2 * 128 + c * 4];
        ushort4 v3 = *(const ushort4*)&hb_in[(size_t)s3 * 128 + c * 4];
        a0 += (b2f(v0.x) + b2f(v1.x)) + (b2f(v2.x) + b2f(v3.x));
        a1 += (b2f(v0.y) + b2f(v1.y)) + (b2f(v2.y) + b2f(v3.y));
        a2 += (b2f(v0.z) + b2f(v1.z)) + (b2f(v2.z) + b2f(v3.z));
        a3 += (b2f(v0.w) + b2f(v1.w)) + (b2f(v2.w) + b2f(v3.w));
      }
      for (; j < end; ++j) {
        int s0 = csr_src[j];
        ushort4 v0 = *(const ushort4*)&hb_in[(size_t)s0 * 128 + c * 4];
        a0 += b2f(v0.x); a1 += b2f(v0.y); a2 += b2f(v0.z); a3 += b2f(v0.w);
      }
      float inv = invdeg[gn];
      ushort4 pv = *(const ushort4*)&pb_in[(size_t)gn * 128 + c * 4];
      float4 bv = *(const float4*)&bias_prev[c * 4];
      ushort4 o;
      o.x = f2b(fmaxf(b2f(pv.x) + a0 * inv + bv.x, 0.f));
      o.y = f2b(fmaxf(b2f(pv.y) + a1 * inv + bv.y, 0.f));
      o.z = f2b(fmaxf(b2f(pv.z) + a2 * inv + bv.z, 0.f));
      o.w = f2b(fmaxf(b2f(pv.w) + a3 * inv + bv.w, 0.f));
      *(ushort4*)&xs[r * 232 + c * 4] = o;
    }
  }
  __syncthreads();

  int w = t >> 6, l = t & 63;
  int c0 = w * 64;
  int lr = l & 15;
  int lk = (l >> 4) * 8;

  float4v acc[4][4];
#pragma unroll
  for (int mt = 0; mt < 4; ++mt)
#pragma unroll
    for (int nt = 0; nt < 4; ++nt)
      acc[mt][nt] = (float4v){0.f, 0.f, 0.f, 0.f};

#pragma unroll
  for (int ks = 0; ks < 7; ++ks) {
    short8v a[4], b[4];
#pragma unroll
    for (int nt = 0; nt < 4; ++nt)
      b[nt] = *(const short8v*)&Wt[(size_t)(c0 + nt * 16 + lr) * 224 + ks * 32 + lk];
#pragma unroll
    for (int mt = 0; mt < 4; ++mt)
      a[mt] = *(const short8v*)&xs[(mt * 16 + lr) * 232 + ks * 32 + lk];
#pragma unroll
    for (int mt = 0; mt < 4; ++mt)
#pragma unroll
      for (int nt = 0; nt < 4; ++nt)
        acc[mt][nt] = __builtin_amdgcn_mfma_f32_16x16x32_bf16(
            a[mt], b[nt], acc[mt][nt], 0, 0, 0);
  }

  // store: C layout col=lane&15, row=(lane>>4)*4+j
  int rbase = (l >> 4) * 4;
#pragma unroll
  for (int mt = 0; mt < 4; ++mt) {
#pragma unroll
    for (int nt = 0; nt < 4; ++nt) {
      int col = c0 + nt * 16 + lr;
#pragma unroll
      for (int j = 0; j < 4; ++j) {
        int row = n0 + mt * 16 + rbase + j;
        if (row < nN) {
          float v = acc[mt][nt][j];
          if (col < 128) hb_out[(size_t)row * 128 + col] = f2b(v);
          else           pb_out[(size_t)row * 128 + (col - 128)] = f2b(v);
        }
      }
    }
  }
}

// ---- final: f4 = relu(pb + invdeg*sum(hb[src]) + b); emit f4@Wln and f4@Wls+bl
__global__ __launch_bounds__(256) void k_gather_fin(
    const unsigned short* __restrict__ hb, const int* __restrict__ row_ptr,
    const int* __restrict__ csr_src, const float* __restrict__ invdeg,
    const unsigned short* __restrict__ pb, const float* __restrict__ bias,
    const float* __restrict__ Wln, const float* __restrict__ Wls,
    const float* __restrict__ bl, float4* __restrict__ h3,
    float4* __restrict__ s3, int nN) {
  int t = blockIdx.x * 256 + threadIdx.x;
  int n = t >> 5, c = t & 31;  // cols 4c..4c+3
  if (n >= nN) return;
  int beg = row_ptr[n], end = row_ptr[n + 1];
  float a0 = 0, a1 = 0, a2 = 0, a3 = 0;
  int j = beg;
  for (; j + 3 < end; j += 4) {
    int s0 = csr_src[j], s1 = csr_src[j + 1];
    int s2 = csr_src[j + 2], sx = csr_src[j + 3];
    ushort4 v0 = *(const ushort4*)&hb[(size_t)s0 * 128 + c * 4];
    ushort4 v1 = *(const ushort4*)&hb[(size_t)s1 * 128 + c * 4];
    ushort4 v2 = *(const ushort4*)&hb[(size_t)s2 * 128 + c * 4];
    ushort4 v3 = *(const ushort4*)&hb[(size_t)sx * 128 + c * 4];
    a0 += (b2f(v0.x) + b2f(v1.x)) + (b2f(v2.x) + b2f(v3.x));
    a1 += (b2f(v0.y) + b2f(v1.y)) + (b2f(v2.y) + b2f(v3.y));
    a2 += (b2f(v0.z) + b2f(v1.z)) + (b2f(v2.z) + b2f(v3.z));
    a3 += (b2f(v0.w) + b2f(v1.w)) + (b2f(v2.w) + b2f(v3.w));
  }
  for (; j < end; ++j) {
    int s0 = csr_src[j];
    ushort4 v0 = *(const ushort4*)&hb[(size_t)s0 * 128 + c * 4];
    a0 += b2f(v0.x); a1 += b2f(v0.y); a2 += b2f(v0.z); a3 += b2f(v0.w);
  }
  float inv = invdeg[n];
  ushort4 pv = *(const ushort4*)&pb[(size_t)n * 128 + c * 4];
  float4 bv = *(const float4*)&bias[c * 4];
  float f0 = fmaxf(b2f(pv.x) + a0 * inv + bv.x, 0.f);
  float f1 = fmaxf(b2f(pv.y) + a1 * inv + bv.y, 0.f);
  float f2 = fmaxf(b2f(pv.z) + a2 * inv + bv.z, 0.f);
  float f3 = fmaxf(b2f(pv.w) + a3 * inv + bv.w, 0.f);
  // bf16-round f to match reference dataflow granularity of prior rounds
  f0 = b2f(f2b(f0)); f1 = b2f(f2b(f1)); f2 = b2f(f2b(f2)); f3 = b2f(f2b(f3));
  float pn[3], ps[3];
  int cc = c * 4;
#pragma unroll
  for (int o = 0; o < 3; ++o) {
    pn[o] = f0 * Wln[cc * 3 + o] + f1 * Wln[(cc + 1) * 3 + o] +
            f2 * Wln[(cc + 2) * 3 + o] + f3 * Wln[(cc + 3) * 3 + o];
    ps[o] = f0 * Wls[cc * 3 + o] + f1 * Wls[(cc + 1) * 3 + o] +
            f2 * Wls[(cc + 2) * 3 + o] + f3 * Wls[(cc + 3) * 3 + o];
  }
#pragma unroll
  for (int off = 16; off >= 1; off >>= 1) {
    pn[0] += __shfl_xor(pn[0], off); pn[1] += __shfl_xor(pn[1], off);
    pn[2] += __shfl_xor(pn[2], off);
    ps[0] += __shfl_xor(ps[0], off); ps[1] += __shfl_xor(ps[1], off);
    ps[2] += __shfl_xor(ps[2], off);
  }
  if (c == 0) {
    float4 hv = {pn[0], pn[1], pn[2], 0.0f};
    float4 sv = {ps[0] + bl[0], ps[1] + bl[1], ps[2] + bl[2], 0.0f};
    h3[n] = hv;
    s3[n] = sv;
  }
}

// ---------------- out[n] = s3[n] + invdeg[n]*sum h3[src] ----------------
__global__ __launch_bounds__(256) void k_out(
    const float4* __restrict__ h3, const float4* __restrict__ s3,
    const int* __restrict__ row_ptr, const int* __restrict__ csr_src,
    const float* __restrict__ invdeg, float* __restrict__ out, int nN) {
  int n = blockIdx.x * 256 + threadIdx.x;
  if (n >= nN) return;
  int beg = row_ptr[n], end = row_ptr[n + 1];
  float4 acc = {0, 0, 0, 0};
  for (int j = beg; j < end; ++j) {
    float4 v = h3[csr_src[j]];
    acc.x += v.x; acc.y += v.y; acc.z += v.z;
  }
  float inv = invdeg[n];
  float4 sv = s3[n];
  out[n * 3 + 0] = sv.x + acc.x * inv;
  out[n * 3 + 1] = sv.y + acc.y * inv;
  out[n * 3 + 2] = sv.z + acc.z * inv;
}

extern "C" void kernel_launch(void* const* d_in, const int* in_sizes, int n_in,
                              void* d_out, int out_size, void* d_ws, size_t ws_size,
                              hipStream_t stream) {
  const float* vert = (const float*)d_in[0];
  const int* edges = (const int*)d_in[1];
  const float* vp = (const float*)d_in[2];
  const float* z = (const float*)d_in[3];
  const float* W0s = (const float*)d_in[4];
  const float* W0n = (const float*)d_in[5];
  const float* b0 = (const float*)d_in[6];
  const float* Wbs = (const float*)d_in[7];
  const float* Wbn = (const float*)d_in[8];
  const float* bb = (const float*)d_in[9];
  const float* Wls = (const float*)d_in[10];
  const float* Wln = (const float*)d_in[11];
  const float* bl = (const float*)d_in[12];
  int nN = in_sizes[0] / 3;
  int nE = in_sizes[1] / 2;

  float* ws = (float*)d_ws;
  size_t o = 0;
  float* invdeg = ws + o; o += (size_t)nN;
  float* nb_in = ws + o; o += (size_t)nN * 6;
  o = (o + 3) & ~(size_t)3;
  unsigned short* fb = (unsigned short*)(ws + o); o += (size_t)nN * 64;
  unsigned short* hbA = (unsigned short*)(ws + o); o += (size_t)nN * 64;
  unsigned short* pbA = (unsigned short*)(ws + o); o += (size_t)nN * 64;
  unsigned short* hbB = (unsigned short*)(ws + o); o += (size_t)nN * 64;
  unsigned short* pbB = (unsigned short*)(ws + o); o += (size_t)nN * 64;
  unsigned short* Wt = (unsigned short*)(ws + o); o += (size_t)4 * 256 * 224 / 2;
  float* h3 = ws + o; o += (size_t)nN * 4;
  float* s3 = ws + o; o += (size_t)nN * 4;
  int* ibase = (int*)(ws + o);
  int* count = ibase;              // nN
  int* row_ptr = ibase + nN;       // nN+1 (+pad)
  int* cursor = row_ptr + nN + 4;  // nN
  int* pscan = cursor + nN;        // 512
  int* csr_src = pscan + 512;      // nE

  int nbScan = (nN + 255) / 256;

  hipMemsetAsync(count, 0, (size_t)nN * sizeof(int), stream);
  k_hist<<<(nE + 255) / 256, 256, 0, stream>>>(edges, count, nE);
  k_scan_part<<<nbScan, 256, 0, stream>>>(count, pscan, nN);
  k_scan_mid<<<1, 512, 0, stream>>>(pscan, row_ptr, nbScan, nN, nE);
  k_scan_out<<<nbScan, 256, 0, stream>>>(count, pscan, row_ptr, cursor, invdeg, nN);
  k_fill<<<(nE + 255) / 256, 256, 0, stream>>>(edges, cursor, csr_src, nE);
  k_prepw<<<(4 * 256 * 224 + 255) / 256, 256, 0, stream>>>(Wbn, Wbs, Wt);

  k_nbin<<<nbScan, 256, 0, stream>>>(row_ptr, csr_src, vert, vp, invdeg, nb_in, nN);
  k_layer0<<<(int)(((size_t)nN * 128 + 255) / 256), 256, 0, stream>>>(
      vert, vp, nb_in, W0s, W0n, b0, fb, nN);

  int nbF = (nN + 63) / 64;
  // m=0: f0 from fb -> hA, pA
  k_fused<0><<<nbF, 256, 0, stream>>>(
      fb, nullptr, nullptr, row_ptr, csr_src, invdeg, b0 /*unused*/,
      z + (size_t)0 * nN * 64, vert, vp, Wt + (size_t)0 * 256 * 224,
      pbA, hbA, nN);
  // m=1: gather(hA,pA,bb0) -> hB, pB
  k_fused<1><<<nbF, 256, 0, stream>>>(
      nullptr, hbA, pbA, row_ptr, csr_src, invdeg, bb + 0 * 128,
      z + (size_t)1 * nN * 64, vert, vp, Wt + (size_t)1 * 256 * 224,
      pbB, hbB, nN);
  // m=2: gather(hB,pB,bb1) -> hA, pA
  k_fused<1><<<nbF, 256, 0, stream>>>(
      nullptr, hbB, pbB, row_ptr, csr_src, invdeg, bb + 1 * 128,
      z + (size_t)2 * nN * 64, vert, vp, Wt + (size_t)2 * 256 * 224,
      pbA, hbA, nN);
  // m=3: gather(hA,pA,bb2) -> hB, pB
  k_fused<1><<<nbF, 256, 0, stream>>>(
      nullptr, hbA, pbA, row_ptr, csr_src, invdeg, bb + 2 * 128,
      z + (size_t)3 * nN * 64, vert, vp, Wt + (size_t)3 * 256 * 224,
      pbB, hbB, nN);
  // final activation + both projections
  k_gather_fin<<<(int)(((size_t)nN * 32 + 255) / 256), 256, 0, stream>>>(
      hbB, row_ptr, csr_src, invdeg, pbB, bb + 3 * 128, Wln, Wls, bl,
      (float4*)h3, (float4*)s3, nN);
  k_out<<<nbScan, 256, 0, stream>>>(
      (const float4*)h3, (const float4*)s3, row_ptr, csr_src, invdeg,
      (float*)d_out, nN);
}

// Round 7
// 557.169 us; speedup vs baseline: 1.3441x; 1.2630x over previous
//
#include <hip/hip_runtime.h>
#include <hip/hip_bf16.h>

// N=100000, E=600000, H=128, Z=64, IN=6, K=224 ([f(128)|z(64)|in(6)|pad(26)]).
// Structure (round-4 revert + fixes): per layer, k_mfma (K=224 fused [h|p] GEMM,
// LDS-repacked coalesced stores) then k_gather_ep (unroll-8 dummy-row gather,
// writes f bf16). Final layer: k_gather_fin emits both 3-wide projections in
// regs; k_out aggregates. CSR gather, no atomics in the hot path.

typedef short short8v __attribute__((ext_vector_type(8)));
typedef float float4v __attribute__((ext_vector_type(4)));

static __device__ __forceinline__ unsigned short f2b(float x) {
  union { float f; unsigned u; } v; v.f = x;
  unsigned r = v.u + 0x7FFF + ((v.u >> 16) & 1);
  return (unsigned short)(r >> 16);
}
static __device__ __forceinline__ float b2f(unsigned short x) {
  union { unsigned u; float f; } v; v.u = ((unsigned)x) << 16;
  return v.f;
}

// ---------------- CSR build ----------------
__global__ __launch_bounds__(256) void k_hist(
    const int* __restrict__ edges, int* __restrict__ count, int nE) {
  int e = blockIdx.x * blockDim.x + threadIdx.x;
  if (e >= nE) return;
  atomicAdd(&count[edges[2 * e + 1]], 1);
}

__global__ __launch_bounds__(256) void k_scan_part(
    const int* __restrict__ count, int* __restrict__ partial, int nN) {
  __shared__ int s[256];
  int t = threadIdx.x;
  int n = blockIdx.x * 256 + t;
  s[t] = (n < nN) ? count[n] : 0;
  __syncthreads();
  for (int off = 128; off > 0; off >>= 1) {
    if (t < off) s[t] += s[t + off];
    __syncthreads();
  }
  if (t == 0) partial[blockIdx.x] = s[0];
}

__global__ __launch_bounds__(512) void k_scan_mid(
    int* __restrict__ partial, int* __restrict__ row_ptr, int nb, int nN, int nE) {
  __shared__ int s[512];
  int t = threadIdx.x;
  int v = (t < nb) ? partial[t] : 0;
  s[t] = v;
  __syncthreads();
  for (int off = 1; off < 512; off <<= 1) {
    int add = (t >= off) ? s[t - off] : 0;
    __syncthreads();
    s[t] += add;
    __syncthreads();
  }
  if (t < nb) partial[t] = s[t] - v;  // exclusive
  if (t == 0) row_ptr[nN] = nE;
}

__global__ __launch_bounds__(256) void k_scan_out(
    const int* __restrict__ count, const int* __restrict__ partial,
    int* __restrict__ row_ptr, int* __restrict__ cursor,
    float* __restrict__ invdeg, int nN) {
  __shared__ int s[256];
  int t = threadIdx.x;
  int n = blockIdx.x * 256 + t;
  int v = (n < nN) ? count[n] : 0;
  s[t] = v;
  __syncthreads();
  for (int off = 1; off < 256; off <<= 1) {
    int add = (t >= off) ? s[t - off] : 0;
    __syncthreads();
    s[t] += add;
    __syncthreads();
  }
  if (n < nN) {
    int excl = s[t] - v + partial[blockIdx.x];
    row_ptr[n] = excl;
    cursor[n] = excl;
    invdeg[n] = 1.0f / fmaxf((float)v, 1.0f);
  }
}

__global__ __launch_bounds__(256) void k_fill(
    const int* __restrict__ edges, int* __restrict__ cursor,
    int* __restrict__ csr_src, int nE) {
  int e = blockIdx.x * blockDim.x + threadIdx.x;
  if (e >= nE) return;
  int src = edges[2 * e], dst = edges[2 * e + 1];
  int pos = atomicAdd(&cursor[dst], 1);
  csr_src[pos] = src;
}

// ---- weight prep: Wt[i][col 256][k 224] bf16; also zero dummy rows ----
__global__ __launch_bounds__(256) void k_prepw(
    const float* __restrict__ Wbn, const float* __restrict__ Wbs,
    unsigned short* __restrict__ Wt, unsigned short* __restrict__ hb,
    float* __restrict__ h3, int nN) {
  int t = blockIdx.x * 256 + threadIdx.x;
  if (blockIdx.x == 0 && threadIdx.x < 128)
    hb[(size_t)nN * 128 + threadIdx.x] = 0;  // dummy h row (gather padding)
  if (blockIdx.x == 1 && threadIdx.x < 4)
    h3[(size_t)nN * 4 + threadIdx.x] = 0.f;  // dummy h3 row
  if (t >= 4 * 256 * 224) return;
  int k = t % 224;
  int c = (t / 224) % 256;
  int i = t / (224 * 256);
  float v = 0.f;
  if (k < 198)
    v = (c < 128) ? Wbn[((size_t)i * 198 + k) * 128 + c]
                  : Wbs[((size_t)i * 198 + k) * 128 + (c - 128)];
  Wt[t] = f2b(v);
}

// ---------------- input-feature aggregation (6 feats) ----------------
__global__ __launch_bounds__(256) void k_nbin(
    const int* __restrict__ row_ptr, const int* __restrict__ csr_src,
    const float* __restrict__ vert, const float* __restrict__ vp,
    const float* __restrict__ invdeg, float* __restrict__ nb_in, int nN) {
  int n = blockIdx.x * blockDim.x + threadIdx.x;
  if (n >= nN) return;
  float a[6] = {0, 0, 0, 0, 0, 0};
  int beg = row_ptr[n], end = row_ptr[n + 1];
  for (int j = beg; j < end; ++j) {
    int s = csr_src[j];
#pragma unroll
    for (int k = 0; k < 3; ++k) {
      a[k] += vert[s * 3 + k];
      a[3 + k] += vp[s * 3 + k];
    }
  }
  float inv = invdeg[n];
#pragma unroll
  for (int k = 0; k < 6; ++k) nb_in[n * 6 + k] = a[k] * inv;
}

// ---------------- layer 0 (K=12, writes bf16 f0) ----------------
__global__ __launch_bounds__(256) void k_layer0(
    const float* __restrict__ vert, const float* __restrict__ vp,
    const float* __restrict__ nb_in, const float* __restrict__ W0s,
    const float* __restrict__ W0n, const float* __restrict__ b0,
    unsigned short* __restrict__ fb, int nN) {
  int t = blockIdx.x * blockDim.x + threadIdx.x;
  int n = t >> 7, hh = t & 127;
  if (n >= nN) return;
  float acc = b0[hh];
#pragma unroll
  for (int k = 0; k < 3; ++k) {
    acc += vert[n * 3 + k] * W0s[k * 128 + hh];
    acc += vp[n * 3 + k] * W0s[(3 + k) * 128 + hh];
    acc += nb_in[n * 6 + k] * W0n[k * 128 + hh];
    acc += nb_in[n * 6 + 3 + k] * W0n[(3 + k) * 128 + hh];
  }
  fb[(size_t)n * 128 + hh] = f2b(fmaxf(acc, 0.0f));
}

// ---------------- fused MFMA GEMM: [h | p] = [f,z,in] @ [Wn | Ws] -------------
// x row (K=224): [f(128) | z(64) | vert(3) vp(3) | 0-pad(26)]
// Block: 64 rows x 256 cols, 4 waves. Staging pitch 232; repack pitch 264.
__global__ __launch_bounds__(256) void k_mfma(
    const unsigned short* __restrict__ fb, const float* __restrict__ z,
    const float* __restrict__ vert, const float* __restrict__ vp,
    const unsigned short* __restrict__ Wt, unsigned short* __restrict__ pb,
    unsigned short* __restrict__ hb, int nN) {
  __shared__ unsigned short xs[64 * 264];
  int t = threadIdx.x;
  int n0 = blockIdx.x * 64;

  // stage f (cols 0..127), 16B per thread-iter
  for (int i = t; i < 64 * 16; i += 256) {
    int r = i >> 4, ck = (i & 15) * 8;
    int gn = min(n0 + r, nN - 1);
    *(short8v*)&xs[r * 232 + ck] = *(const short8v*)&fb[(size_t)gn * 128 + ck];
  }
  // stage z (cols 128..191), f32->bf16
  for (int i = t; i < 64 * 16; i += 256) {
    int r = i >> 4, ck = (i & 15) * 4;
    int gn = min(n0 + r, nN - 1);
    float4 v = *(const float4*)&z[(size_t)gn * 64 + ck];
    ushort4 o = {f2b(v.x), f2b(v.y), f2b(v.z), f2b(v.w)};
    *(ushort4*)&xs[r * 232 + 128 + ck] = o;
  }
  // stage in (cols 192..197) + zero pad (198..223)
  for (int i = t; i < 64 * 16; i += 256) {
    int r = i >> 4, p = i & 15;
    int c = 192 + 2 * p;
    int gn = min(n0 + r, nN - 1);
    float v0 = 0.f, v1 = 0.f;
    if (c < 198)     v0 = (c < 195) ? vert[gn * 3 + c - 192] : vp[gn * 3 + c - 195];
    if (c + 1 < 198) v1 = (c + 1 < 195) ? vert[gn * 3 + c - 191] : vp[gn * 3 + c - 194];
    ushort2 o = {f2b(v0), f2b(v1)};
    *(ushort2*)&xs[r * 232 + c] = o;
  }
  __syncthreads();

  int w = t >> 6, l = t & 63;
  int c0 = w * 64;
  int lr = l & 15;
  int lk = (l >> 4) * 8;

  float4v acc[4][4];
#pragma unroll
  for (int mt = 0; mt < 4; ++mt)
#pragma unroll
    for (int nt = 0; nt < 4; ++nt)
      acc[mt][nt] = (float4v){0.f, 0.f, 0.f, 0.f};

#pragma unroll
  for (int ks = 0; ks < 7; ++ks) {
    short8v a[4], b[4];
#pragma unroll
    for (int nt = 0; nt < 4; ++nt)
      b[nt] = *(const short8v*)&Wt[(size_t)(c0 + nt * 16 + lr) * 224 + ks * 32 + lk];
#pragma unroll
    for (int mt = 0; mt < 4; ++mt)
      a[mt] = *(const short8v*)&xs[(mt * 16 + lr) * 232 + ks * 32 + lk];
#pragma unroll
    for (int mt = 0; mt < 4; ++mt)
#pragma unroll
      for (int nt = 0; nt < 4; ++nt)
        acc[mt][nt] = __builtin_amdgcn_mfma_f32_16x16x32_bf16(
            a[mt], b[nt], acc[mt][nt], 0, 0, 0);
  }

  // repack through LDS: C layout col=lane&15, row=(lane>>4)*4+j
  __syncthreads();  // staging data dead; safe to overwrite
  int rbase = (l >> 4) * 4;
#pragma unroll
  for (int mt = 0; mt < 4; ++mt)
#pragma unroll
    for (int nt = 0; nt < 4; ++nt) {
      int col = c0 + nt * 16 + lr;
#pragma unroll
      for (int j = 0; j < 4; ++j)
        xs[(mt * 16 + rbase + j) * 264 + col] = f2b(acc[mt][nt][j]);
    }
  __syncthreads();
  // cooperative coalesced store: 64 rows x 32 chunks of 16B (h: 16, p: 16)
  for (int i = t; i < 64 * 32; i += 256) {
    int r = i >> 5, ch = i & 31;
    int gn = n0 + r;
    if (gn < nN) {
      short8v v = *(short8v*)&xs[r * 264 + ch * 8];
      if (ch < 16) *(short8v*)&hb[(size_t)gn * 128 + ch * 8] = v;
      else         *(short8v*)&pb[(size_t)gn * 128 + (ch - 16) * 8] = v;
    }
  }
}

// ---- gather h + epilogue: f = relu(p + invdeg*sum(h[src]) + b), unroll-8 ----
__global__ __launch_bounds__(256) void k_gather_ep(
    const unsigned short* __restrict__ hb, const int* __restrict__ row_ptr,
    const int* __restrict__ csr_src, const float* __restrict__ invdeg,
    const unsigned short* __restrict__ pb, const float* __restrict__ bias,
    unsigned short* __restrict__ fb, int nN) {
  int t = blockIdx.x * 256 + threadIdx.x;
  int n = t >> 5, c = t & 31;  // cols 4c..4c+3
  if (n >= nN) return;
  int beg = row_ptr[n], end = row_ptr[n + 1];
  float a0 = 0, a1 = 0, a2 = 0, a3 = 0;
  for (int j = beg; j < end; j += 8) {
    int s[8];
#pragma unroll
    for (int u = 0; u < 8; ++u) {
      int jj = j + u;
      int idx = csr_src[jj < end ? jj : end - 1];
      s[u] = (jj < end) ? idx : nN;  // nN = zero dummy row
    }
    ushort4 v[8];
#pragma unroll
    for (int u = 0; u < 8; ++u)
      v[u] = *(const ushort4*)&hb[(size_t)s[u] * 128 + c * 4];
#pragma unroll
    for (int u = 0; u < 8; ++u) {
      a0 += b2f(v[u].x); a1 += b2f(v[u].y);
      a2 += b2f(v[u].z); a3 += b2f(v[u].w);
    }
  }
  float inv = invdeg[n];
  ushort4 pv = *(const ushort4*)&pb[(size_t)n * 128 + c * 4];
  float4 bv = *(const float4*)&bias[c * 4];
  ushort4 o;
  o.x = f2b(fmaxf(b2f(pv.x) + a0 * inv + bv.x, 0.f));
  o.y = f2b(fmaxf(b2f(pv.y) + a1 * inv + bv.y, 0.f));
  o.z = f2b(fmaxf(b2f(pv.z) + a2 * inv + bv.z, 0.f));
  o.w = f2b(fmaxf(b2f(pv.w) + a3 * inv + bv.w, 0.f));
  *(ushort4*)&fb[(size_t)n * 128 + c * 4] = o;
}

// ---- final: f4 = relu(p + invdeg*sum(h[src]) + b); emit f4@Wln, f4@Wls+bl ----
__global__ __launch_bounds__(256) void k_gather_fin(
    const unsigned short* __restrict__ hb, const int* __restrict__ row_ptr,
    const int* __restrict__ csr_src, const float* __restrict__ invdeg,
    const unsigned short* __restrict__ pb, const float* __restrict__ bias,
    const float* __restrict__ Wln, const float* __restrict__ Wls,
    const float* __restrict__ bl, float4* __restrict__ h3,
    float4* __restrict__ s3, int nN) {
  int t = blockIdx.x * 256 + threadIdx.x;
  int n = t >> 5, c = t & 31;
  if (n >= nN) return;
  int beg = row_ptr[n], end = row_ptr[n + 1];
  float a0 = 0, a1 = 0, a2 = 0, a3 = 0;
  for (int j = beg; j < end; j += 8) {
    int s[8];
#pragma unroll
    for (int u = 0; u < 8; ++u) {
      int jj = j + u;
      int idx = csr_src[jj < end ? jj : end - 1];
      s[u] = (jj < end) ? idx : nN;
    }
    ushort4 v[8];
#pragma unroll
    for (int u = 0; u < 8; ++u)
      v[u] = *(const ushort4*)&hb[(size_t)s[u] * 128 + c * 4];
#pragma unroll
    for (int u = 0; u < 8; ++u) {
      a0 += b2f(v[u].x); a1 += b2f(v[u].y);
      a2 += b2f(v[u].z); a3 += b2f(v[u].w);
    }
  }
  float inv = invdeg[n];
  ushort4 pv = *(const ushort4*)&pb[(size_t)n * 128 + c * 4];
  float4 bv = *(const float4*)&bias[c * 4];
  float f0 = fmaxf(b2f(pv.x) + a0 * inv + bv.x, 0.f);
  float f1 = fmaxf(b2f(pv.y) + a1 * inv + bv.y, 0.f);
  float f2 = fmaxf(b2f(pv.z) + a2 * inv + bv.z, 0.f);
  float f3 = fmaxf(b2f(pv.w) + a3 * inv + bv.w, 0.f);
  f0 = b2f(f2b(f0)); f1 = b2f(f2b(f1)); f2 = b2f(f2b(f2)); f3 = b2f(f2b(f3));
  float pn[3], ps[3];
  int cc = c * 4;
#pragma unroll
  for (int o = 0; o < 3; ++o) {
    pn[o] = f0 * Wln[cc * 3 + o] + f1 * Wln[(cc + 1) * 3 + o] +
            f2 * Wln[(cc + 2) * 3 + o] + f3 * Wln[(cc + 3) * 3 + o];
    ps[o] = f0 * Wls[cc * 3 + o] + f1 * Wls[(cc + 1) * 3 + o] +
            f2 * Wls[(cc + 2) * 3 + o] + f3 * Wls[(cc + 3) * 3 + o];
  }
#pragma unroll
  for (int off = 16; off >= 1; off >>= 1) {
    pn[0] += __shfl_xor(pn[0], off); pn[1] += __shfl_xor(pn[1], off);
    pn[2] += __shfl_xor(pn[2], off);
    ps[0] += __shfl_xor(ps[0], off); ps[1] += __shfl_xor(ps[1], off);
    ps[2] += __shfl_xor(ps[2], off);
  }
  if (c == 0) {
    float4 hv = {pn[0], pn[1], pn[2], 0.0f};
    float4 sv = {ps[0] + bl[0], ps[1] + bl[1], ps[2] + bl[2], 0.0f};
    h3[n] = hv;
    s3[n] = sv;
  }
}

// ---------------- out[n] = s3[n] + invdeg[n]*sum h3[src], unroll-4 ----------
__global__ __launch_bounds__(256) void k_out(
    const float4* __restrict__ h3, const float4* __restrict__ s3,
    const int* __restrict__ row_ptr, const int* __restrict__ csr_src,
    const float* __restrict__ invdeg, float* __restrict__ out, int nN) {
  int n = blockIdx.x * 256 + threadIdx.x;
  if (n >= nN) return;
  int beg = row_ptr[n], end = row_ptr[n + 1];
  float ax = 0, ay = 0, az = 0;
  for (int j = beg; j < end; j += 4) {
    int s[4];
#pragma unroll
    for (int u = 0; u < 4; ++u) {
      int jj = j + u;
      int idx = csr_src[jj < end ? jj : end - 1];
      s[u] = (jj < end) ? idx : nN;  // h3 dummy row = 0
    }
    float4 v[4];
#pragma unroll
    for (int u = 0; u < 4; ++u) v[u] = h3[s[u]];
#pragma unroll
    for (int u = 0; u < 4; ++u) { ax += v[u].x; ay += v[u].y; az += v[u].z; }
  }
  float inv = invdeg[n];
  float4 sv = s3[n];
  out[n * 3 + 0] = sv.x + ax * inv;
  out[n * 3 + 1] = sv.y + ay * inv;
  out[n * 3 + 2] = sv.z + az * inv;
}

extern "C" void kernel_launch(void* const* d_in, const int* in_sizes, int n_in,
                              void* d_out, int out_size, void* d_ws, size_t ws_size,
                              hipStream_t stream) {
  const float* vert = (const float*)d_in[0];
  const int* edges = (const int*)d_in[1];
  const float* vp = (const float*)d_in[2];
  const float* z = (const float*)d_in[3];
  const float* W0s = (const float*)d_in[4];
  const float* W0n = (const float*)d_in[5];
  const float* b0 = (const float*)d_in[6];
  const float* Wbs = (const float*)d_in[7];
  const float* Wbn = (const float*)d_in[8];
  const float* bb = (const float*)d_in[9];
  const float* Wls = (const float*)d_in[10];
  const float* Wln = (const float*)d_in[11];
  const float* bl = (const float*)d_in[12];
  int nN = in_sizes[0] / 3;
  int nE = in_sizes[1] / 2;

  float* ws = (float*)d_ws;
  size_t o = 0;
  float* invdeg = ws + o; o += (size_t)nN;
  float* nb_in = ws + o; o += (size_t)nN * 6;
  o = (o + 3) & ~(size_t)3;
  unsigned short* fb = (unsigned short*)(ws + o); o += (size_t)nN * 64;
  unsigned short* hb = (unsigned short*)(ws + o); o += (size_t)(nN + 1) * 64;  // +dummy row
  unsigned short* pb = (unsigned short*)(ws + o); o += (size_t)nN * 64;
  unsigned short* Wt = (unsigned short*)(ws + o); o += (size_t)4 * 256 * 224 / 2;
  float* h3 = ws + o; o += (size_t)(nN + 1) * 4;  // +dummy row
  float* s3 = ws + o; o += (size_t)nN * 4;
  int* ibase = (int*)(ws + o);
  int* count = ibase;              // nN
  int* row_ptr = ibase + nN;       // nN+1 (+pad)
  int* cursor = row_ptr + nN + 4;  // nN
  int* pscan = cursor + nN;        // 512
  int* csr_src = pscan + 512;      // nE

  int nbScan = (nN + 255) / 256;

  hipMemsetAsync(count, 0, (size_t)nN * sizeof(int), stream);
  k_hist<<<(nE + 255) / 256, 256, 0, stream>>>(edges, count, nE);
  k_scan_part<<<nbScan, 256, 0, stream>>>(count, pscan, nN);
  k_scan_mid<<<1, 512, 0, stream>>>(pscan, row_ptr, nbScan, nN, nE);
  k_scan_out<<<nbScan, 256, 0, stream>>>(count, pscan, row_ptr, cursor, invdeg, nN);
  k_fill<<<(nE + 255) / 256, 256, 0, stream>>>(edges, cursor, csr_src, nE);
  k_prepw<<<(4 * 256 * 224 + 255) / 256, 256, 0, stream>>>(Wbn, Wbs, Wt, hb, h3, nN);

  k_nbin<<<nbScan, 256, 0, stream>>>(row_ptr, csr_src, vert, vp, invdeg, nb_in, nN);
  k_layer0<<<(int)(((size_t)nN * 128 + 255) / 256), 256, 0, stream>>>(
      vert, vp, nb_in, W0s, W0n, b0, fb, nN);

  int nbF = (nN + 63) / 64;
  int nbG = (int)(((size_t)nN * 32 + 255) / 256);
  for (int i = 0; i < 4; ++i) {
    k_mfma<<<nbF, 256, 0, stream>>>(
        fb, z + (size_t)i * nN * 64, vert, vp, Wt + (size_t)i * 256 * 224,
        pb, hb, nN);
    if (i < 3)
      k_gather_ep<<<nbG, 256, 0, stream>>>(
          hb, row_ptr, csr_src, invdeg, pb, bb + (size_t)i * 128, fb, nN);
    else
      k_gather_fin<<<nbG, 256, 0, stream>>>(
          hb, row_ptr, csr_src, invdeg, pb, bb + (size_t)i * 128, Wln, Wls, bl,
          (float4*)h3, (float4*)s3, nN);
  }

  k_out<<<nbScan, 256, 0, stream>>>(
      (const float4*)h3, (const float4*)s3, row_ptr, csr_src, invdeg,
      (float*)d_out, nN);
}